// Round 21
// baseline (199.641 us; speedup 1.0000x reference)
//
#include <hip/hip_runtime.h>
#include <hip/hip_bf16.h>

// Problem constants (GAT_18176301597437)
#define N_NODES 4096
#define F_IN    256
#define KH      8
#define KF      512          // KH*FPH
#define NEG_SLOPE 0.2f
#define EBIAS   4.0f

typedef _Float16 half8v __attribute__((ext_vector_type(8)));   // MFMA f16 A/B
typedef _Float16 half2v __attribute__((ext_vector_type(2)));   // packed f16 pair
typedef __attribute__((ext_vector_type(4))) float floatx4;     // MFMA C/D + NT stores

union H8U4 { half8v v; unsigned u[4]; };

__device__ __forceinline__ unsigned short f2h(float f) {
    _Float16 h = (_Float16)f;
    unsigned short u; __builtin_memcpy(&u, &h, 2);
    return u;
}
__device__ __forceinline__ half2v asH2(unsigned u) {
    half2v h; __builtin_memcpy(&h, &u, 4);
    return h;
}
__device__ __forceinline__ unsigned asU(half2v h) {
    unsigned u; __builtin_memcpy(&u, &h, 4);
    return u;
}
// load 8 consecutive fp32, convert to f16 fragment
__device__ __forceinline__ half8v ld8f(const float* p) {
    const float4 a = *(const float4*)p;
    const float4 b = *(const float4*)(p + 4);
    half8v h;
    h[0] = (_Float16)a.x; h[1] = (_Float16)a.y;
    h[2] = (_Float16)a.z; h[3] = (_Float16)a.w;
    h[4] = (_Float16)b.x; h[5] = (_Float16)b.y;
    h[6] = (_Float16)b.z; h[7] = (_Float16)b.w;
    return h;
}

// ---------- device body: mask passthrough + bit-pack, 8 int4 per thread ------
// 8 outstanding 16B loads/thread (batched) -> 8 independent shfl-OR trees.
// outm stores are non-temporal (write-only stream).
__device__ __forceinline__ void mask_body8(
    size_t bid, int tid,
    const int* __restrict__ mask, float* __restrict__ outm,
    unsigned long long* __restrict__ bits) {
  const size_t base = bid * 2048 + tid;   // int4 index, chunk stride 256
  int4 mv[8];
  #pragma unroll
  for (int c = 0; c < 8; ++c) mv[c] = ((const int4*)mask)[base + c * 256];
  #pragma unroll
  for (int c = 0; c < 8; ++c) {
    const size_t t4 = base + c * 256;
    floatx4 o;
    o[0] = mv[c].x ? 1.f : 0.f; o[1] = mv[c].y ? 1.f : 0.f;
    o[2] = mv[c].z ? 1.f : 0.f; o[3] = mv[c].w ? 1.f : 0.f;
    __builtin_nontemporal_store(o, (floatx4*)outm + t4);
    const unsigned nib = (mv[c].x ? 1u : 0u) | (mv[c].y ? 2u : 0u) |
                         (mv[c].z ? 4u : 0u) | (mv[c].w ? 8u : 0u);
    unsigned long long wv = (unsigned long long)nib << (4 * (tid & 15));
    wv |= __shfl_xor(wv, 1);
    wv |= __shfl_xor(wv, 2);
    wv |= __shfl_xor(wv, 4);
    wv |= __shfl_xor(wv, 8);
    if ((tid & 15) == 0) {
      const size_t e0 = t4 << 2;            // first element of this 64-group
      const size_t n = e0 >> 12;
      const size_t cc = (e0 & 4095) >> 6;
      bits[cc * N_NODES + n] = wv;
    }
  }
}

// ---------- device body: MFMA xe-GEMM + fused hl/EA/EB/bmax epilogue ---------
__device__ __forceinline__ void xe_body(
    int bx, int k, int tid,
    const float* __restrict__ x,
    const float* __restrict__ Ww,
    const float* __restrict__ Wb,
    const float* __restrict__ al,
    const float* __restrict__ ar,
    unsigned short* __restrict__ xeB,
    float* __restrict__ hl,             // [8][4096]
    unsigned* __restrict__ EA,          // [8][2048]
    unsigned* __restrict__ EB,          // [8][2048]
    float* __restrict__ bmax) {         // [8][256]
  const int w = tid >> 6;               // wave = 16-row group
  const int lane = tid & 63;
  const int col16 = lane & 15;
  const int quad = lane >> 4;
  const int n0 = bx * 64;

  const int rowA = n0 + w * 16 + col16;
  const float* xp  = x  + (size_t)rowA * F_IN + quad * 8;
  const float* wwp = Ww + (size_t)(k * 64 + col16) * F_IN + quad * 8;

  floatx4 acc[4];
  #pragma unroll
  for (int ft = 0; ft < 4; ++ft) acc[ft] = (floatx4){0.f, 0.f, 0.f, 0.f};

  #pragma unroll
  for (int ks = 0; ks < 8; ++ks) {
    const half8v aF = ld8f(xp + ks * 32);
    #pragma unroll
    for (int ft = 0; ft < 4; ++ft) {
      const half8v bF = ld8f(wwp + (size_t)(ft * 16) * F_IN + ks * 32);
      acc[ft] = __builtin_amdgcn_mfma_f32_16x16x32_f16(aF, bF, acc[ft], 0, 0, 0);
    }
  }

  float pl[4] = {0.f, 0.f, 0.f, 0.f};
  float pr[4] = {0.f, 0.f, 0.f, 0.f};
  const int xoff = (w >> 1) * 512 + col16 * 32
                 + ((w & 1) * 2 + (quad >> 1)) * 8 + (quad & 1) * 4;
  #pragma unroll
  for (int ft = 0; ft < 4; ++ft) {
    const int c = k * 64 + ft * 16 + col16;
    const float wbv = Wb[c];
    const float a_l = al[c];
    const float a_r = ar[c];
    float v[4];
    ushort4 pk;
    #pragma unroll
    for (int i = 0; i < 4; ++i) {
      v[i] = acc[ft][i] + wbv;
      pl[i] = fmaf(v[i], a_l, pl[i]);
      pr[i] = fmaf(v[i], a_r, pr[i]);
    }
    pk.x = f2h(v[0]); pk.y = f2h(v[1]); pk.z = f2h(v[2]); pk.w = f2h(v[3]);
    unsigned short* tile = xeB + ((((size_t)(k * 4 + ft)) * 64 + bx) << 10);
    *(ushort4*)(tile + xoff) = pk;
  }
  #pragma unroll
  for (int o = 8; o > 0; o >>= 1) {
    #pragma unroll
    for (int i = 0; i < 4; ++i) {
      pl[i] += __shfl_xor(pl[i], o);
      pr[i] += __shfl_xor(pr[i], o);
    }
  }
  if (col16 == 0) {
    const int n = n0 + w * 16 + quad * 4;   // 4 consecutive rows
    float4 o0 = {pl[0], pl[1], pl[2], pl[3]};
    *(float4*)(hl + k * N_NODES + n) = o0;
    unsigned short e1[4], e2[4];
    #pragma unroll
    for (int i = 0; i < 4; ++i) {
      e1[i] = f2h(__expf(pr[i] - EBIAS));
      e2[i] = f2h(__expf(NEG_SLOPE * (pr[i] - EBIAS)));
    }
    uint2 wa, wbv2;
    wa.x   = (unsigned)e1[0] | ((unsigned)e1[1] << 16);
    wa.y   = (unsigned)e1[2] | ((unsigned)e1[3] << 16);
    wbv2.x = (unsigned)e2[0] | ((unsigned)e2[1] << 16);
    wbv2.y = (unsigned)e2[2] | ((unsigned)e2[3] << 16);
    *(uint2*)(EA + k * 2048 + (n >> 1)) = wa;
    *(uint2*)(EB + k * 2048 + (n >> 1)) = wbv2;
  }
  float bm = (col16 == 0)
      ? fmaxf(fmaxf(pr[0], pr[1]), fmaxf(pr[2], pr[3])) : -1e30f;
  bm = fmaxf(bm, __shfl_xor(bm, 16));
  bm = fmaxf(bm, __shfl_xor(bm, 32));
  if (lane == 0) bmax[k * 256 + bx * 4 + w] = bm;
}

// ---------- preamble: xe blocks first (compute) + mask stream (HBM) ----------
__global__ __launch_bounds__(256) void preamble(
    const int* __restrict__ mask, float* __restrict__ outm,
    unsigned long long* __restrict__ bits,
    const float* __restrict__ x, const float* __restrict__ Ww,
    const float* __restrict__ Wb, const float* __restrict__ al,
    const float* __restrict__ ar, unsigned short* __restrict__ xeB,
    float* __restrict__ hl, unsigned* __restrict__ EA,
    unsigned* __restrict__ EB, float* __restrict__ bmax) {
  if (blockIdx.x < 512) {
    xe_body((int)(blockIdx.x & 63), (int)(blockIdx.x >> 6), threadIdx.x,
            x, Ww, Wb, al, ar, xeB, hl, EA, EB, bmax);
  } else {
    mask_body8((size_t)blockIdx.x - 512, threadIdx.x, mask, outm, bits);
  }
}

// ---------- fallback kernels (scratch inside out_mask region) ----------
__global__ __launch_bounds__(256) void xe_gemm_k(
    const float* __restrict__ x, const float* __restrict__ Ww,
    const float* __restrict__ Wb, const float* __restrict__ al,
    const float* __restrict__ ar, unsigned short* __restrict__ xeB,
    float* __restrict__ hl, unsigned* __restrict__ EA,
    unsigned* __restrict__ EB, float* __restrict__ bmax) {
  xe_body(blockIdx.x, blockIdx.y, threadIdx.x,
          x, Ww, Wb, al, ar, xeB, hl, EA, EB, bmax);
}
__global__ __launch_bounds__(256) void mask_pack(
    const int* __restrict__ mask, unsigned long long* __restrict__ bits) {
  const size_t idx = (size_t)blockIdx.x * 256 + threadIdx.x;
  const unsigned long long b = __ballot(mask[idx] != 0);
  if ((threadIdx.x & 63) == 0) {
    const size_t w = idx >> 6;
    bits[(w & 63) * (size_t)N_NODES + (w >> 6)] = b;
  }
}
__global__ __launch_bounds__(256) void mask_copy(
    const int* __restrict__ mask, float* __restrict__ outm) {
  const size_t i4 = (size_t)blockIdx.x * 256 + threadIdx.x;
  const int4 mv = ((const int4*)mask)[i4];
  float4 o;
  o.x = mv.x ? 1.f : 0.f; o.y = mv.y ? 1.f : 0.f;
  o.z = mv.z ? 1.f : 0.f; o.w = mv.w ? 1.f : 0.f;
  ((float4*)outm)[i4] = o;
}

// ---------- Kernel D: fused attention, 32 rows/block, full 1-deep pipeline ---
__global__ __launch_bounds__(256, 2) void gat_attn(
    const unsigned long long* __restrict__ mbitsT,   // [64 c][4096 n]
    const float* __restrict__ hl,
    const float* __restrict__ bmax,                  // [8][256]
    const unsigned* __restrict__ EA,                 // [8][2048] f16 pairs
    const unsigned* __restrict__ EB,
    const unsigned short* __restrict__ xeB,          // f16 frag tiles
    float* __restrict__ out) {
  __shared__ float lds_acc[4][64][20];   // 20 KB (reused for both phases)
  const int t = threadIdx.x;
  const int w4 = t >> 6;                // wave 0..3 = m-quarter
  const int lane = t & 63;
  const int k  = blockIdx.x & 7;        // XCD-pinned head
  const int rg = blockIdx.x >> 3;
  const int n0 = rg * 32;
  const int row = lane & 15;
  const int quad = lane >> 4;
  const int q8 = quad * 8;

  const float4 bm4 = ((const float4*)bmax)[k * 64 + lane];
  float hm = fmaxf(fmaxf(bm4.x, bm4.y), fmaxf(bm4.z, bm4.w));
  #pragma unroll
  for (int o = 1; o < 64; o <<= 1) hm = fmaxf(hm, __shfl_xor(hm, o));

  const float* hlp = hl + k * N_NODES + n0 + row;
  const float hlA = hlp[0];
  const float hlB = hlp[16];
  const float sA = hlA + hm;
  const float MA = fmaxf(sA, NEG_SLOPE * sA);
  const float sB = hlB + hm;
  const float MB = fmaxf(sB, NEG_SLOPE * sB);
  const float c1Af = __expf(hlA + EBIAS - MA);
  const float c2Af = __expf(NEG_SLOPE * (hlA + EBIAS) - MA);
  const float c1Bf = __expf(hlB + EBIAS - MB);
  const float c2Bf = __expf(NEG_SLOPE * (hlB + EBIAS) - MB);
  const half2v c1A = {(_Float16)c1Af, (_Float16)c1Af};
  const half2v c2A = {(_Float16)c2Af, (_Float16)c2Af};
  const half2v c1B = {(_Float16)c1Bf, (_Float16)c1Bf};
  const half2v c2B = {(_Float16)c2Bf, (_Float16)c2Bf};

  const int c0 = w4 * 16;
  const int cEnd = c0 + 16;

  // running pointers
  const unsigned* pEA = EA + k * 2048 + c0 * 32 + quad * 4;
  const unsigned* pEB = EB + k * 2048 + c0 * 32 + quad * 4;
  const unsigned long long* pM = mbitsT + (size_t)c0 * N_NODES + n0 + row;
  const unsigned short* pB = xeB + (((size_t)k * 4) << 16)
                           + ((size_t)c0 << 10) + row * 32 + q8;

  half8v ones;
  #pragma unroll
  for (int i = 0; i < 8; ++i) ones[i] = (_Float16)1.0f;

  floatx4 accA[4], accB[4];
  #pragma unroll
  for (int ft = 0; ft < 4; ++ft) {
    accA[ft] = (floatx4){0.f, 0.f, 0.f, 0.f};
    accB[ft] = (floatx4){0.f, 0.f, 0.f, 0.f};
  }
  floatx4 dpA = (floatx4){0.f, 0.f, 0.f, 0.f};
  floatx4 dpB = (floatx4){0.f, 0.f, 0.f, 0.f};

  // prefetch chunk c0: B frags, EA lo/hi, EB lo/hi, both mask words
  half8v nb0, nb1, nb2, nb3, nb4, nb5, nb6, nb7;
  nb0 = *(const half8v*)pB;                     nb1 = *(const half8v*)(pB + 512);
  nb2 = *(const half8v*)(pB + (64 << 10));      nb3 = *(const half8v*)(pB + (64 << 10) + 512);
  nb4 = *(const half8v*)(pB + (128 << 10));     nb5 = *(const half8v*)(pB + (128 << 10) + 512);
  nb6 = *(const half8v*)(pB + (192 << 10));     nb7 = *(const half8v*)(pB + (192 << 10) + 512);
  pB += 1024;
  uint4 pA0 = *(const uint4*)pEA;
  uint4 pA1 = *(const uint4*)(pEA + 16);
  uint4 pB0 = *(const uint4*)pEB;
  uint4 pB1 = *(const uint4*)(pEB + 16);
  unsigned long long pMvA = pM[0];
  unsigned long long pMvB = pM[16];

  for (int cc = c0; cc < cEnd; ++cc) {
    // ---- consume prefetched B; prefetch next chunk's B ----
    const half8v b0 = nb0, b1 = nb1, b2 = nb2, b3 = nb3;
    const half8v b4 = nb4, b5 = nb5, b6 = nb6, b7 = nb7;
    const uint4 eA0 = pA0, eA1 = pA1, eB0 = pB0, eB1 = pB1;
    const unsigned long long mbA = pMvA, mbB = pMvB;
    pEA += 32; pEB += 32; pM += N_NODES;
    if (cc + 1 < cEnd) {
      nb0 = *(const half8v*)pB;                     nb1 = *(const half8v*)(pB + 512);
      nb2 = *(const half8v*)(pB + (64 << 10));      nb3 = *(const half8v*)(pB + (64 << 10) + 512);
      nb4 = *(const half8v*)(pB + (128 << 10));     nb5 = *(const half8v*)(pB + (128 << 10) + 512);
      nb6 = *(const half8v*)(pB + (192 << 10));     nb7 = *(const half8v*)(pB + (192 << 10) + 512);
      pB += 1024;
      pA0 = *(const uint4*)pEA;
      pA1 = *(const uint4*)(pEA + 16);
      pB0 = *(const uint4*)pEB;
      pB1 = *(const uint4*)(pEB + 16);
      pMvA = pM[0];
      pMvB = pM[16];
    }
    const unsigned ea_lo[4] = {eA0.x, eA0.y, eA0.z, eA0.w};
    const unsigned eb_lo[4] = {eB0.x, eB0.y, eB0.z, eB0.w};
    const unsigned ea_hi[4] = {eA1.x, eA1.y, eA1.z, eA1.w};
    const unsigned eb_hi[4] = {eB1.x, eB1.y, eB1.z, eB1.w};
    // ---- tile A: w-compute + MFMAs ----
    {
      const unsigned mlo = (unsigned)(mbA >> q8);
      const unsigned mhi = (unsigned)(mbA >> (32 + q8));
      H8U4 a0, a1;
      #pragma unroll
      for (int p = 0; p < 4; ++p) {
        const half2v w2 = __builtin_elementwise_max(c1A * asH2(ea_lo[p]),
                                                    c2A * asH2(eb_lo[p]));
        const unsigned tb = mlo >> (2 * p);
        a0.u[p] = asU(w2) & (((tb & 1u) | ((tb & 2u) << 15)) * 0xFFFFu);
      }
      #pragma unroll
      for (int p = 0; p < 4; ++p) {
        const half2v w2 = __builtin_elementwise_max(c1A * asH2(ea_hi[p]),
                                                    c2A * asH2(eb_hi[p]));
        const unsigned tb = mhi >> (2 * p);
        a1.u[p] = asU(w2) & (((tb & 1u) | ((tb & 2u) << 15)) * 0xFFFFu);
      }
      dpA = __builtin_amdgcn_mfma_f32_16x16x32_f16(a0.v, ones, dpA, 0, 0, 0);
      dpA = __builtin_amdgcn_mfma_f32_16x16x32_f16(a1.v, ones, dpA, 0, 0, 0);
      accA[0] = __builtin_amdgcn_mfma_f32_16x16x32_f16(a0.v, b0, accA[0], 0, 0, 0);
      accA[0] = __builtin_amdgcn_mfma_f32_16x16x32_f16(a1.v, b1, accA[0], 0, 0, 0);
      accA[1] = __builtin_amdgcn_mfma_f32_16x16x32_f16(a0.v, b2, accA[1], 0, 0, 0);
      accA[1] = __builtin_amdgcn_mfma_f32_16x16x32_f16(a1.v, b3, accA[1], 0, 0, 0);
      accA[2] = __builtin_amdgcn_mfma_f32_16x16x32_f16(a0.v, b4, accA[2], 0, 0, 0);
      accA[2] = __builtin_amdgcn_mfma_f32_16x16x32_f16(a1.v, b5, accA[2], 0, 0, 0);
      accA[3] = __builtin_amdgcn_mfma_f32_16x16x32_f16(a0.v, b6, accA[3], 0, 0, 0);
      accA[3] = __builtin_amdgcn_mfma_f32_16x16x32_f16(a1.v, b7, accA[3], 0, 0, 0);
    }
    // ---- tile B: w-compute + MFMAs (reuses E regs + B frags) ----
    {
      const unsigned mlo = (unsigned)(mbB >> q8);
      const unsigned mhi = (unsigned)(mbB >> (32 + q8));
      H8U4 a0, a1;
      #pragma unroll
      for (int p = 0; p < 4; ++p) {
        const half2v w2 = __builtin_elementwise_max(c1B * asH2(ea_lo[p]),
                                                    c2B * asH2(eb_lo[p]));
        const unsigned tb = mlo >> (2 * p);
        a0.u[p] = asU(w2) & (((tb & 1u) | ((tb & 2u) << 15)) * 0xFFFFu);
      }
      #pragma unroll
      for (int p = 0; p < 4; ++p) {
        const half2v w2 = __builtin_elementwise_max(c1B * asH2(ea_hi[p]),
                                                    c2B * asH2(eb_hi[p]));
        const unsigned tb = mhi >> (2 * p);
        a1.u[p] = asU(w2) & (((tb & 1u) | ((tb & 2u) << 15)) * 0xFFFFu);
      }
      dpB = __builtin_amdgcn_mfma_f32_16x16x32_f16(a0.v, ones, dpB, 0, 0, 0);
      dpB = __builtin_amdgcn_mfma_f32_16x16x32_f16(a1.v, ones, dpB, 0, 0, 0);
      accB[0] = __builtin_amdgcn_mfma_f32_16x16x32_f16(a0.v, b0, accB[0], 0, 0, 0);
      accB[0] = __builtin_amdgcn_mfma_f32_16x16x32_f16(a1.v, b1, accB[0], 0, 0, 0);
      accB[1] = __builtin_amdgcn_mfma_f32_16x16x32_f16(a0.v, b2, accB[1], 0, 0, 0);
      accB[1] = __builtin_amdgcn_mfma_f32_16x16x32_f16(a1.v, b3, accB[1], 0, 0, 0);
      accB[2] = __builtin_amdgcn_mfma_f32_16x16x32_f16(a0.v, b4, accB[2], 0, 0, 0);
      accB[2] = __builtin_amdgcn_mfma_f32_16x16x32_f16(a1.v, b5, accB[2], 0, 0, 0);
      accB[3] = __builtin_amdgcn_mfma_f32_16x16x32_f16(a0.v, b6, accB[3], 0, 0, 0);
      accB[3] = __builtin_amdgcn_mfma_f32_16x16x32_f16(a1.v, b7, accB[3], 0, 0, 0);
    }
  }

  // ---- phase A epilogue (rows n0..n0+15) ----
  #pragma unroll
  for (int i = 0; i < 16; ++i) lds_acc[w4][lane][i] = accA[i >> 2][i & 3];
  #pragma unroll
  for (int i = 0; i < 4; ++i) lds_acc[w4][lane][16 + i] = dpA[i];
  __syncthreads();
  #pragma unroll
  for (int j = 0; j < 4; ++j) {
    const int sl = 4 * w4 + j;
    float fa = 0.f, dpt = 0.f;
    #pragma unroll
    for (int w2 = 0; w2 < 4; ++w2) {
      fa  += lds_acc[w2][lane][sl];
      dpt += lds_acc[w2][lane][16 + j];
    }
    float v = fa / dpt;
    v = (v > 0.f) ? v : (__expf(v) - 1.f);
    v = (v > 0.f) ? v : (__expf(v) - 1.f);
    out[(size_t)(n0 + quad * 4 + j) * KF + k * 64 + w4 * 16 + row] = v;
  }
  __syncthreads();
  // ---- phase B epilogue (rows n0+16..n0+31) ----
  #pragma unroll
  for (int i = 0; i < 16; ++i) lds_acc[w4][lane][i] = accB[i >> 2][i & 3];
  #pragma unroll
  for (int i = 0; i < 4; ++i) lds_acc[w4][lane][16 + i] = dpB[i];
  __syncthreads();
  #pragma unroll
  for (int j = 0; j < 4; ++j) {
    const int sl = 4 * w4 + j;
    float fa = 0.f, dpt = 0.f;
    #pragma unroll
    for (int w2 = 0; w2 < 4; ++w2) {
      fa  += lds_acc[w2][lane][sl];
      dpt += lds_acc[w2][lane][16 + j];
    }
    float v = fa / dpt;
    v = (v > 0.f) ? v : (__expf(v) - 1.f);
    v = (v > 0.f) ? v : (__expf(v) - 1.f);
    out[(size_t)(n0 + 16 + quad * 4 + j) * KF + k * 64 + w4 * 16 + row] = v;
  }
}

// ---------- launcher ----------
extern "C" void kernel_launch(void* const* d_in, const int* in_sizes, int n_in,
                              void* d_out, int out_size, void* d_ws, size_t ws_size,
                              hipStream_t stream) {
  const float* x    = (const float*)d_in[0];   // (4096,256) fp32
  const float* Ww   = (const float*)d_in[1];   // (512,256)  fp32
  const float* Wb   = (const float*)d_in[2];   // (512,)     fp32
  const float* al   = (const float*)d_in[3];   // (1,8,64)   fp32
  const float* ar   = (const float*)d_in[4];   // (1,8,64)   fp32
  const int*   mask = (const int*)d_in[5];     // (1,4096,4096) int32

  float* out      = (float*)d_out;                    // (4096,512) fp32, 8 MB
  float* out_mask = out + (size_t)N_NODES * KF;       // (1,4096,4096) fp32, 64 MB

  const bool use_ws = (ws_size >= (8u << 20));
  char* scratch = use_ws ? (char*)d_ws : (char*)out_mask;
  unsigned short* xeB  = (unsigned short*)scratch;                 // 4 MB
  float*          hl   = (float*)(scratch + (4u << 20));           // 128 KB
  unsigned*       EA   = (unsigned*)(hl + KH * N_NODES);           // 64 KB
  unsigned*       EB   = EA + KH * 2048;                           // 64 KB
  float*          bmax = (float*)(EB + KH * 2048);                 // 8 KB
  unsigned long long* mbitsT = (unsigned long long*)(scratch + (5u << 20)); // 2 MB
  // top of use: 7 MB

  if (use_ws) {
    // fused preamble: 512 xe blocks (compute) + 2048 mask blocks (8x int4/thr)
    preamble<<<512 + (N_NODES * (size_t)N_NODES) / 8192, 256, 0, stream>>>(
        mask, out_mask, mbitsT, x, Ww, Wb, al, ar, xeB, hl, EA, EB, bmax);
    gat_attn<<<128 * KH, 256, 0, stream>>>(mbitsT, hl, bmax, EA, EB, xeB, out);
  } else {
    dim3 ga(N_NODES / 64, KH);
    xe_gemm_k<<<ga, 256, 0, stream>>>(x, Ww, Wb, al, ar, xeB, hl, EA, EB, bmax);
    mask_pack<<<(N_NODES * (size_t)N_NODES) / 256, 256, 0, stream>>>(mask, mbitsT);
    gat_attn<<<128 * KH, 256, 0, stream>>>(mbitsT, hl, bmax, EA, EB, xeB, out);
    mask_copy<<<(N_NODES * (size_t)N_NODES) / (4 * 256), 256, 0, stream>>>(mask, out_mask);
  }
}

// Round 22
// 198.687 us; speedup vs baseline: 1.0048x; 1.0048x over previous
//
#include <hip/hip_runtime.h>
#include <hip/hip_bf16.h>

// Problem constants (GAT_18176301597437)
#define N_NODES 4096
#define F_IN    256
#define KH      8
#define KF      512          // KH*FPH
#define NEG_SLOPE 0.2f
#define EBIAS   4.0f

typedef _Float16 half8v __attribute__((ext_vector_type(8)));   // MFMA f16 A/B
typedef _Float16 half2v __attribute__((ext_vector_type(2)));   // packed f16 pair
typedef __attribute__((ext_vector_type(4))) float floatx4;     // MFMA C/D + NT stores

union H8U4 { half8v v; unsigned u[4]; };

__device__ __forceinline__ unsigned short f2h(float f) {
    _Float16 h = (_Float16)f;
    unsigned short u; __builtin_memcpy(&u, &h, 2);
    return u;
}
__device__ __forceinline__ half2v asH2(unsigned u) {
    half2v h; __builtin_memcpy(&h, &u, 4);
    return h;
}
__device__ __forceinline__ unsigned asU(half2v h) {
    unsigned u; __builtin_memcpy(&u, &h, 4);
    return u;
}
// load 8 consecutive fp32, convert to f16 fragment
__device__ __forceinline__ half8v ld8f(const float* p) {
    const float4 a = *(const float4*)p;
    const float4 b = *(const float4*)(p + 4);
    half8v h;
    h[0] = (_Float16)a.x; h[1] = (_Float16)a.y;
    h[2] = (_Float16)a.z; h[3] = (_Float16)a.w;
    h[4] = (_Float16)b.x; h[5] = (_Float16)b.y;
    h[6] = (_Float16)b.z; h[7] = (_Float16)b.w;
    return h;
}

// ---------- device body: mask passthrough + bit-pack, 4 int4 per thread ------
// Batched loads (4 outstanding 16B loads/thread) -> 4 independent shfl-OR
// trees. outm stores are non-temporal (write-only stream).
__device__ __forceinline__ void mask_body4(
    size_t bid, int tid,
    const int* __restrict__ mask, float* __restrict__ outm,
    unsigned long long* __restrict__ bits) {
  const size_t base = bid * 1024 + tid;   // int4 index, chunk stride 256
  int4 mv[4];
  #pragma unroll
  for (int c = 0; c < 4; ++c) mv[c] = ((const int4*)mask)[base + c * 256];
  #pragma unroll
  for (int c = 0; c < 4; ++c) {
    const size_t t4 = base + c * 256;
    floatx4 o;
    o[0] = mv[c].x ? 1.f : 0.f; o[1] = mv[c].y ? 1.f : 0.f;
    o[2] = mv[c].z ? 1.f : 0.f; o[3] = mv[c].w ? 1.f : 0.f;
    __builtin_nontemporal_store(o, (floatx4*)outm + t4);
    const unsigned nib = (mv[c].x ? 1u : 0u) | (mv[c].y ? 2u : 0u) |
                         (mv[c].z ? 4u : 0u) | (mv[c].w ? 8u : 0u);
    unsigned long long wv = (unsigned long long)nib << (4 * (tid & 15));
    wv |= __shfl_xor(wv, 1);
    wv |= __shfl_xor(wv, 2);
    wv |= __shfl_xor(wv, 4);
    wv |= __shfl_xor(wv, 8);
    if ((tid & 15) == 0) {
      const size_t e0 = t4 << 2;            // first element of this 64-group
      const size_t n = e0 >> 12;
      const size_t cc = (e0 & 4095) >> 6;
      bits[cc * N_NODES + n] = wv;
    }
  }
}

// ---------- device body: MFMA xe-GEMM + fused hl/EA/EB/bmax epilogue ---------
__device__ __forceinline__ void xe_body(
    int bx, int k, int tid,
    const float* __restrict__ x,
    const float* __restrict__ Ww,
    const float* __restrict__ Wb,
    const float* __restrict__ al,
    const float* __restrict__ ar,
    unsigned short* __restrict__ xeB,
    float* __restrict__ hl,             // [8][4096]
    unsigned* __restrict__ EA,          // [8][2048]
    unsigned* __restrict__ EB,          // [8][2048]
    float* __restrict__ bmax) {         // [8][256]
  const int w = tid >> 6;               // wave = 16-row group
  const int lane = tid & 63;
  const int col16 = lane & 15;
  const int quad = lane >> 4;
  const int n0 = bx * 64;

  const int rowA = n0 + w * 16 + col16;
  const float* xp  = x  + (size_t)rowA * F_IN + quad * 8;
  const float* wwp = Ww + (size_t)(k * 64 + col16) * F_IN + quad * 8;

  floatx4 acc[4];
  #pragma unroll
  for (int ft = 0; ft < 4; ++ft) acc[ft] = (floatx4){0.f, 0.f, 0.f, 0.f};

  #pragma unroll
  for (int ks = 0; ks < 8; ++ks) {
    const half8v aF = ld8f(xp + ks * 32);
    #pragma unroll
    for (int ft = 0; ft < 4; ++ft) {
      const half8v bF = ld8f(wwp + (size_t)(ft * 16) * F_IN + ks * 32);
      acc[ft] = __builtin_amdgcn_mfma_f32_16x16x32_f16(aF, bF, acc[ft], 0, 0, 0);
    }
  }

  float pl[4] = {0.f, 0.f, 0.f, 0.f};
  float pr[4] = {0.f, 0.f, 0.f, 0.f};
  const int xoff = (w >> 1) * 512 + col16 * 32
                 + ((w & 1) * 2 + (quad >> 1)) * 8 + (quad & 1) * 4;
  #pragma unroll
  for (int ft = 0; ft < 4; ++ft) {
    const int c = k * 64 + ft * 16 + col16;
    const float wbv = Wb[c];
    const float a_l = al[c];
    const float a_r = ar[c];
    float v[4];
    ushort4 pk;
    #pragma unroll
    for (int i = 0; i < 4; ++i) {
      v[i] = acc[ft][i] + wbv;
      pl[i] = fmaf(v[i], a_l, pl[i]);
      pr[i] = fmaf(v[i], a_r, pr[i]);
    }
    pk.x = f2h(v[0]); pk.y = f2h(v[1]); pk.z = f2h(v[2]); pk.w = f2h(v[3]);
    unsigned short* tile = xeB + ((((size_t)(k * 4 + ft)) * 64 + bx) << 10);
    *(ushort4*)(tile + xoff) = pk;
  }
  #pragma unroll
  for (int o = 8; o > 0; o >>= 1) {
    #pragma unroll
    for (int i = 0; i < 4; ++i) {
      pl[i] += __shfl_xor(pl[i], o);
      pr[i] += __shfl_xor(pr[i], o);
    }
  }
  if (col16 == 0) {
    const int n = n0 + w * 16 + quad * 4;   // 4 consecutive rows
    float4 o0 = {pl[0], pl[1], pl[2], pl[3]};
    *(float4*)(hl + k * N_NODES + n) = o0;
    unsigned short e1[4], e2[4];
    #pragma unroll
    for (int i = 0; i < 4; ++i) {
      e1[i] = f2h(__expf(pr[i] - EBIAS));
      e2[i] = f2h(__expf(NEG_SLOPE * (pr[i] - EBIAS)));
    }
    uint2 wa, wbv2;
    wa.x   = (unsigned)e1[0] | ((unsigned)e1[1] << 16);
    wa.y   = (unsigned)e1[2] | ((unsigned)e1[3] << 16);
    wbv2.x = (unsigned)e2[0] | ((unsigned)e2[1] << 16);
    wbv2.y = (unsigned)e2[2] | ((unsigned)e2[3] << 16);
    *(uint2*)(EA + k * 2048 + (n >> 1)) = wa;
    *(uint2*)(EB + k * 2048 + (n >> 1)) = wbv2;
  }
  float bm = (col16 == 0)
      ? fmaxf(fmaxf(pr[0], pr[1]), fmaxf(pr[2], pr[3])) : -1e30f;
  bm = fmaxf(bm, __shfl_xor(bm, 16));
  bm = fmaxf(bm, __shfl_xor(bm, 32));
  if (lane == 0) bmax[k * 256 + bx * 4 + w] = bm;
}

// ---------- preamble: xe blocks first (compute) + mask stream (HBM) ----------
__global__ __launch_bounds__(256) void preamble(
    const int* __restrict__ mask, float* __restrict__ outm,
    unsigned long long* __restrict__ bits,
    const float* __restrict__ x, const float* __restrict__ Ww,
    const float* __restrict__ Wb, const float* __restrict__ al,
    const float* __restrict__ ar, unsigned short* __restrict__ xeB,
    float* __restrict__ hl, unsigned* __restrict__ EA,
    unsigned* __restrict__ EB, float* __restrict__ bmax) {
  if (blockIdx.x < 512) {
    xe_body((int)(blockIdx.x & 63), (int)(blockIdx.x >> 6), threadIdx.x,
            x, Ww, Wb, al, ar, xeB, hl, EA, EB, bmax);
  } else {
    mask_body4((size_t)blockIdx.x - 512, threadIdx.x, mask, outm, bits);
  }
}

// ---------- fallback kernels (scratch inside out_mask region) ----------
__global__ __launch_bounds__(256) void xe_gemm_k(
    const float* __restrict__ x, const float* __restrict__ Ww,
    const float* __restrict__ Wb, const float* __restrict__ al,
    const float* __restrict__ ar, unsigned short* __restrict__ xeB,
    float* __restrict__ hl, unsigned* __restrict__ EA,
    unsigned* __restrict__ EB, float* __restrict__ bmax) {
  xe_body(blockIdx.x, blockIdx.y, threadIdx.x,
          x, Ww, Wb, al, ar, xeB, hl, EA, EB, bmax);
}
__global__ __launch_bounds__(256) void mask_pack(
    const int* __restrict__ mask, unsigned long long* __restrict__ bits) {
  const size_t idx = (size_t)blockIdx.x * 256 + threadIdx.x;
  const unsigned long long b = __ballot(mask[idx] != 0);
  if ((threadIdx.x & 63) == 0) {
    const size_t w = idx >> 6;
    bits[(w & 63) * (size_t)N_NODES + (w >> 6)] = b;
  }
}
__global__ __launch_bounds__(256) void mask_copy(
    const int* __restrict__ mask, float* __restrict__ outm) {
  const size_t i4 = (size_t)blockIdx.x * 256 + threadIdx.x;
  const int4 mv = ((const int4*)mask)[i4];
  float4 o;
  o.x = mv.x ? 1.f : 0.f; o.y = mv.y ? 1.f : 0.f;
  o.z = mv.z ? 1.f : 0.f; o.w = mv.w ? 1.f : 0.f;
  ((float4*)outm)[i4] = o;
}

// ---------- Kernel D: fused attention, 32 rows/block, full 1-deep pipeline ---
__global__ __launch_bounds__(256, 2) void gat_attn(
    const unsigned long long* __restrict__ mbitsT,   // [64 c][4096 n]
    const float* __restrict__ hl,
    const float* __restrict__ bmax,                  // [8][256]
    const unsigned* __restrict__ EA,                 // [8][2048] f16 pairs
    const unsigned* __restrict__ EB,
    const unsigned short* __restrict__ xeB,          // f16 frag tiles
    float* __restrict__ out) {
  __shared__ float lds_acc[4][64][20];   // 20 KB (reused for both phases)
  const int t = threadIdx.x;
  const int w4 = t >> 6;                // wave 0..3 = m-quarter
  const int lane = t & 63;
  const int k  = blockIdx.x & 7;        // XCD-pinned head
  const int rg = blockIdx.x >> 3;
  const int n0 = rg * 32;
  const int row = lane & 15;
  const int quad = lane >> 4;
  const int q8 = quad * 8;

  const float4 bm4 = ((const float4*)bmax)[k * 64 + lane];
  float hm = fmaxf(fmaxf(bm4.x, bm4.y), fmaxf(bm4.z, bm4.w));
  #pragma unroll
  for (int o = 1; o < 64; o <<= 1) hm = fmaxf(hm, __shfl_xor(hm, o));

  const float* hlp = hl + k * N_NODES + n0 + row;
  const float hlA = hlp[0];
  const float hlB = hlp[16];
  const float sA = hlA + hm;
  const float MA = fmaxf(sA, NEG_SLOPE * sA);
  const float sB = hlB + hm;
  const float MB = fmaxf(sB, NEG_SLOPE * sB);
  const float c1Af = __expf(hlA + EBIAS - MA);
  const float c2Af = __expf(NEG_SLOPE * (hlA + EBIAS) - MA);
  const float c1Bf = __expf(hlB + EBIAS - MB);
  const float c2Bf = __expf(NEG_SLOPE * (hlB + EBIAS) - MB);
  const half2v c1A = {(_Float16)c1Af, (_Float16)c1Af};
  const half2v c2A = {(_Float16)c2Af, (_Float16)c2Af};
  const half2v c1B = {(_Float16)c1Bf, (_Float16)c1Bf};
  const half2v c2B = {(_Float16)c2Bf, (_Float16)c2Bf};

  const int c0 = w4 * 16;
  const int cEnd = c0 + 16;

  // running pointers
  const unsigned* pEA = EA + k * 2048 + c0 * 32 + quad * 4;
  const unsigned* pEB = EB + k * 2048 + c0 * 32 + quad * 4;
  const unsigned long long* pM = mbitsT + (size_t)c0 * N_NODES + n0 + row;
  const unsigned short* pB = xeB + (((size_t)k * 4) << 16)
                           + ((size_t)c0 << 10) + row * 32 + q8;

  half8v ones;
  #pragma unroll
  for (int i = 0; i < 8; ++i) ones[i] = (_Float16)1.0f;

  floatx4 accA[4], accB[4];
  #pragma unroll
  for (int ft = 0; ft < 4; ++ft) {
    accA[ft] = (floatx4){0.f, 0.f, 0.f, 0.f};
    accB[ft] = (floatx4){0.f, 0.f, 0.f, 0.f};
  }
  floatx4 dpA = (floatx4){0.f, 0.f, 0.f, 0.f};
  floatx4 dpB = (floatx4){0.f, 0.f, 0.f, 0.f};

  // prefetch chunk c0: B frags, EA lo/hi, EB lo/hi, both mask words
  half8v nb0, nb1, nb2, nb3, nb4, nb5, nb6, nb7;
  nb0 = *(const half8v*)pB;                     nb1 = *(const half8v*)(pB + 512);
  nb2 = *(const half8v*)(pB + (64 << 10));      nb3 = *(const half8v*)(pB + (64 << 10) + 512);
  nb4 = *(const half8v*)(pB + (128 << 10));     nb5 = *(const half8v*)(pB + (128 << 10) + 512);
  nb6 = *(const half8v*)(pB + (192 << 10));     nb7 = *(const half8v*)(pB + (192 << 10) + 512);
  pB += 1024;
  uint4 pA0 = *(const uint4*)pEA;
  uint4 pA1 = *(const uint4*)(pEA + 16);
  uint4 pB0 = *(const uint4*)pEB;
  uint4 pB1 = *(const uint4*)(pEB + 16);
  unsigned long long pMvA = pM[0];
  unsigned long long pMvB = pM[16];

  for (int cc = c0; cc < cEnd; ++cc) {
    // ---- consume prefetched B; prefetch next chunk's B ----
    const half8v b0 = nb0, b1 = nb1, b2 = nb2, b3 = nb3;
    const half8v b4 = nb4, b5 = nb5, b6 = nb6, b7 = nb7;
    const uint4 eA0 = pA0, eA1 = pA1, eB0 = pB0, eB1 = pB1;
    const unsigned long long mbA = pMvA, mbB = pMvB;
    pEA += 32; pEB += 32; pM += N_NODES;
    if (cc + 1 < cEnd) {
      nb0 = *(const half8v*)pB;                     nb1 = *(const half8v*)(pB + 512);
      nb2 = *(const half8v*)(pB + (64 << 10));      nb3 = *(const half8v*)(pB + (64 << 10) + 512);
      nb4 = *(const half8v*)(pB + (128 << 10));     nb5 = *(const half8v*)(pB + (128 << 10) + 512);
      nb6 = *(const half8v*)(pB + (192 << 10));     nb7 = *(const half8v*)(pB + (192 << 10) + 512);
      pB += 1024;
      pA0 = *(const uint4*)pEA;
      pA1 = *(const uint4*)(pEA + 16);
      pB0 = *(const uint4*)pEB;
      pB1 = *(const uint4*)(pEB + 16);
      pMvA = pM[0];
      pMvB = pM[16];
    }
    const unsigned ea_lo[4] = {eA0.x, eA0.y, eA0.z, eA0.w};
    const unsigned eb_lo[4] = {eB0.x, eB0.y, eB0.z, eB0.w};
    const unsigned ea_hi[4] = {eA1.x, eA1.y, eA1.z, eA1.w};
    const unsigned eb_hi[4] = {eB1.x, eB1.y, eB1.z, eB1.w};
    // ---- tile A: w-compute + MFMAs ----
    {
      const unsigned mlo = (unsigned)(mbA >> q8);
      const unsigned mhi = (unsigned)(mbA >> (32 + q8));
      H8U4 a0, a1;
      #pragma unroll
      for (int p = 0; p < 4; ++p) {
        const half2v w2 = __builtin_elementwise_max(c1A * asH2(ea_lo[p]),
                                                    c2A * asH2(eb_lo[p]));
        const unsigned tb = mlo >> (2 * p);
        a0.u[p] = asU(w2) & (((tb & 1u) | ((tb & 2u) << 15)) * 0xFFFFu);
      }
      #pragma unroll
      for (int p = 0; p < 4; ++p) {
        const half2v w2 = __builtin_elementwise_max(c1A * asH2(ea_hi[p]),
                                                    c2A * asH2(eb_hi[p]));
        const unsigned tb = mhi >> (2 * p);
        a1.u[p] = asU(w2) & (((tb & 1u) | ((tb & 2u) << 15)) * 0xFFFFu);
      }
      dpA = __builtin_amdgcn_mfma_f32_16x16x32_f16(a0.v, ones, dpA, 0, 0, 0);
      dpA = __builtin_amdgcn_mfma_f32_16x16x32_f16(a1.v, ones, dpA, 0, 0, 0);
      accA[0] = __builtin_amdgcn_mfma_f32_16x16x32_f16(a0.v, b0, accA[0], 0, 0, 0);
      accA[0] = __builtin_amdgcn_mfma_f32_16x16x32_f16(a1.v, b1, accA[0], 0, 0, 0);
      accA[1] = __builtin_amdgcn_mfma_f32_16x16x32_f16(a0.v, b2, accA[1], 0, 0, 0);
      accA[1] = __builtin_amdgcn_mfma_f32_16x16x32_f16(a1.v, b3, accA[1], 0, 0, 0);
      accA[2] = __builtin_amdgcn_mfma_f32_16x16x32_f16(a0.v, b4, accA[2], 0, 0, 0);
      accA[2] = __builtin_amdgcn_mfma_f32_16x16x32_f16(a1.v, b5, accA[2], 0, 0, 0);
      accA[3] = __builtin_amdgcn_mfma_f32_16x16x32_f16(a0.v, b6, accA[3], 0, 0, 0);
      accA[3] = __builtin_amdgcn_mfma_f32_16x16x32_f16(a1.v, b7, accA[3], 0, 0, 0);
    }
    // ---- tile B: w-compute + MFMAs (reuses E regs + B frags) ----
    {
      const unsigned mlo = (unsigned)(mbB >> q8);
      const unsigned mhi = (unsigned)(mbB >> (32 + q8));
      H8U4 a0, a1;
      #pragma unroll
      for (int p = 0; p < 4; ++p) {
        const half2v w2 = __builtin_elementwise_max(c1B * asH2(ea_lo[p]),
                                                    c2B * asH2(eb_lo[p]));
        const unsigned tb = mlo >> (2 * p);
        a0.u[p] = asU(w2) & (((tb & 1u) | ((tb & 2u) << 15)) * 0xFFFFu);
      }
      #pragma unroll
      for (int p = 0; p < 4; ++p) {
        const half2v w2 = __builtin_elementwise_max(c1B * asH2(ea_hi[p]),
                                                    c2B * asH2(eb_hi[p]));
        const unsigned tb = mhi >> (2 * p);
        a1.u[p] = asU(w2) & (((tb & 1u) | ((tb & 2u) << 15)) * 0xFFFFu);
      }
      dpB = __builtin_amdgcn_mfma_f32_16x16x32_f16(a0.v, ones, dpB, 0, 0, 0);
      dpB = __builtin_amdgcn_mfma_f32_16x16x32_f16(a1.v, ones, dpB, 0, 0, 0);
      accB[0] = __builtin_amdgcn_mfma_f32_16x16x32_f16(a0.v, b0, accB[0], 0, 0, 0);
      accB[0] = __builtin_amdgcn_mfma_f32_16x16x32_f16(a1.v, b1, accB[0], 0, 0, 0);
      accB[1] = __builtin_amdgcn_mfma_f32_16x16x32_f16(a0.v, b2, accB[1], 0, 0, 0);
      accB[1] = __builtin_amdgcn_mfma_f32_16x16x32_f16(a1.v, b3, accB[1], 0, 0, 0);
      accB[2] = __builtin_amdgcn_mfma_f32_16x16x32_f16(a0.v, b4, accB[2], 0, 0, 0);
      accB[2] = __builtin_amdgcn_mfma_f32_16x16x32_f16(a1.v, b5, accB[2], 0, 0, 0);
      accB[3] = __builtin_amdgcn_mfma_f32_16x16x32_f16(a0.v, b6, accB[3], 0, 0, 0);
      accB[3] = __builtin_amdgcn_mfma_f32_16x16x32_f16(a1.v, b7, accB[3], 0, 0, 0);
    }
  }

  // ---- phase A epilogue (rows n0..n0+15) ----
  #pragma unroll
  for (int i = 0; i < 16; ++i) lds_acc[w4][lane][i] = accA[i >> 2][i & 3];
  #pragma unroll
  for (int i = 0; i < 4; ++i) lds_acc[w4][lane][16 + i] = dpA[i];
  __syncthreads();
  #pragma unroll
  for (int j = 0; j < 4; ++j) {
    const int sl = 4 * w4 + j;
    float fa = 0.f, dpt = 0.f;
    #pragma unroll
    for (int w2 = 0; w2 < 4; ++w2) {
      fa  += lds_acc[w2][lane][sl];
      dpt += lds_acc[w2][lane][16 + j];
    }
    float v = fa / dpt;
    v = (v > 0.f) ? v : (__expf(v) - 1.f);
    v = (v > 0.f) ? v : (__expf(v) - 1.f);
    out[(size_t)(n0 + quad * 4 + j) * KF + k * 64 + w4 * 16 + row] = v;
  }
  __syncthreads();
  // ---- phase B epilogue (rows n0+16..n0+31) ----
  #pragma unroll
  for (int i = 0; i < 16; ++i) lds_acc[w4][lane][i] = accB[i >> 2][i & 3];
  #pragma unroll
  for (int i = 0; i < 4; ++i) lds_acc[w4][lane][16 + i] = dpB[i];
  __syncthreads();
  #pragma unroll
  for (int j = 0; j < 4; ++j) {
    const int sl = 4 * w4 + j;
    float fa = 0.f, dpt = 0.f;
    #pragma unroll
    for (int w2 = 0; w2 < 4; ++w2) {
      fa  += lds_acc[w2][lane][sl];
      dpt += lds_acc[w2][lane][16 + j];
    }
    float v = fa / dpt;
    v = (v > 0.f) ? v : (__expf(v) - 1.f);
    v = (v > 0.f) ? v : (__expf(v) - 1.f);
    out[(size_t)(n0 + 16 + quad * 4 + j) * KF + k * 64 + w4 * 16 + row] = v;
  }
}

// ---------- launcher ----------
extern "C" void kernel_launch(void* const* d_in, const int* in_sizes, int n_in,
                              void* d_out, int out_size, void* d_ws, size_t ws_size,
                              hipStream_t stream) {
  const float* x    = (const float*)d_in[0];   // (4096,256) fp32
  const float* Ww   = (const float*)d_in[1];   // (512,256)  fp32
  const float* Wb   = (const float*)d_in[2];   // (512,)     fp32
  const float* al   = (const float*)d_in[3];   // (1,8,64)   fp32
  const float* ar   = (const float*)d_in[4];   // (1,8,64)   fp32
  const int*   mask = (const int*)d_in[5];     // (1,4096,4096) int32

  float* out      = (float*)d_out;                    // (4096,512) fp32, 8 MB
  float* out_mask = out + (size_t)N_NODES * KF;       // (1,4096,4096) fp32, 64 MB

  const bool use_ws = (ws_size >= (8u << 20));
  char* scratch = use_ws ? (char*)d_ws : (char*)out_mask;
  unsigned short* xeB  = (unsigned short*)scratch;                 // 4 MB
  float*          hl   = (float*)(scratch + (4u << 20));           // 128 KB
  unsigned*       EA   = (unsigned*)(hl + KH * N_NODES);           // 64 KB
  unsigned*       EB   = EA + KH * 2048;                           // 64 KB
  float*          bmax = (float*)(EB + KH * 2048);                 // 8 KB
  unsigned long long* mbitsT = (unsigned long long*)(scratch + (5u << 20)); // 2 MB
  // top of use: 7 MB

  if (use_ws) {
    // fused preamble: 512 xe blocks (compute) + 4096 mask blocks (4x int4/thr)
    preamble<<<512 + (N_NODES * (size_t)N_NODES) / 4096, 256, 0, stream>>>(
        mask, out_mask, mbitsT, x, Ww, Wb, al, ar, xeB, hl, EA, EB, bmax);
    gat_attn<<<128 * KH, 256, 0, stream>>>(mbitsT, hl, bmax, EA, EB, xeB, out);
  } else {
    dim3 ga(N_NODES / 64, KH);
    xe_gemm_k<<<ga, 256, 0, stream>>>(x, Ww, Wb, al, ar, xeB, hl, EA, EB, bmax);
    mask_pack<<<(N_NODES * (size_t)N_NODES) / 256, 256, 0, stream>>>(mask, mbitsT);
    gat_attn<<<128 * KH, 256, 0, stream>>>(mbitsT, hl, bmax, EA, EB, xeB, out);
    mask_copy<<<(N_NODES * (size_t)N_NODES) / (4 * 256), 256, 0, stream>>>(mask, out_mask);
  }
}